// Round 5
// baseline (2476.127 us; speedup 1.0000x reference)
//
#include <hip/hip_runtime.h>
#include <stdint.h>

typedef unsigned long long u64;
typedef unsigned int u32;
typedef float f2 __attribute__((ext_vector_type(2)));

__device__ __forceinline__ float rn_mul(float a, float b){ return __fmul_rn(a,b); }
__device__ __forceinline__ float rn_add(float a, float b){ return __fadd_rn(a,b); }
__device__ __forceinline__ float rn_sub(float a, float b){ return __fsub_rn(a,b); }

__device__ __forceinline__ float sq3(float dx, float dy, float dz){
  return rn_add(rn_add(rn_mul(dx,dx), rn_mul(dy,dy)), rn_mul(dz,dz));
}

// monotone float->uint key (total order over all floats incl. negatives)
__device__ __forceinline__ u32 fkey(float d){
  u32 b = __float_as_uint(d);
  return b ^ ((u32)((int)b >> 31) | 0x80000000u);
}
__device__ __forceinline__ float unfkey(u32 k){
  const u32 b = (k & 0x80000000u) ? (k ^ 0x80000000u) : ~k;
  return __uint_as_float(b);
}

__device__ __forceinline__ u64 shfl_xor64(u64 v, int mask){
  int lo = __shfl_xor((int)(u32)v, mask, 64);
  int hi = __shfl_xor((int)(u32)(v >> 32), mask, 64);
  return ((u64)(u32)hi << 32) | (u32)lo;
}
__device__ __forceinline__ u64 umin64(u64 a, u64 b){ return a < b ? a : b; }
__device__ __forceinline__ u64 umax64(u64 a, u64 b){ return a > b ? a : b; }

// ---- DPP-based max reductions (VALU pipe) ---------------------------------
template<int C>
__device__ __forceinline__ u32 dstep(u32 v){
  u32 x = (u32)__builtin_amdgcn_update_dpp((int)v, (int)v, C, 0xF, 0xF, false);
  return x > v ? x : v;
}
__device__ __forceinline__ u32 wave64_maxu(u32 v){
  v = dstep<0x111>(v);  // row_shr:1
  v = dstep<0x112>(v);  // row_shr:2
  v = dstep<0x114>(v);  // row_shr:4
  v = dstep<0x118>(v);  // row_shr:8
  v = dstep<0x142>(v);  // row_bcast:15
  v = dstep<0x143>(v);  // row_bcast:31
  return (u32)__builtin_amdgcn_readlane((int)v, 63);
}
template<int C>
__device__ __forceinline__ u64 dstep64(u64 v){
  const u32 l = (u32)__builtin_amdgcn_update_dpp((int)(u32)v, (int)(u32)v, C, 0xF, 0xF, false);
  const u32 h = (u32)__builtin_amdgcn_update_dpp((int)(u32)(v>>32), (int)(u32)(v>>32), C, 0xF, 0xF, false);
  const u64 o = ((u64)h << 32) | l;
  return o > v ? o : v;
}
__device__ __forceinline__ u64 red8_max64(u64 v){
  v = dstep64<0x111>(v);
  v = dstep64<0x112>(v);
  v = dstep64<0x114>(v);
  const u32 l = (u32)__builtin_amdgcn_readlane((int)(u32)v, 7);
  const u32 h = (u32)__builtin_amdgcn_readlane((int)(u32)(v>>32), 7);
  return ((u64)h << 32) | l;
}

__device__ __forceinline__ f2 f2max(f2 a, f2 b){
  f2 r; r.x = fmaxf(a.x,b.x); r.y = fmaxf(a.y,b.y); return r;
}

// ---------------------------------------------------------------------------
// FPS, exact octant pruning, NO global stores inside the loop (the store +
// __syncthreads()'s implied vmcnt(0) drain was the hidden ~1000cy/iter cost).
// Winner indices go to an LDS u16 list; coords written in a parallel epilogue.
// One block per batch; wave w owns sign-octant w (compacted in a single
// float4 LDS table, coords+mind+origidx in registers, tight bbox).
// Skip is exact: every skipped fminf is provably a no-op -> bit-identical.
// ---------------------------------------------------------------------------
template<int N, int NT, int M>
__global__ __launch_bounds__(NT)
void fps_kernel(const float* __restrict__ pts, float* __restrict__ npts)
{
#pragma clang fp contract(off)
  constexpr int NW  = NT / 64;          // 8 waves = 8 octants
  constexpr int CAP = N/8 + 192;        // 1216 slots/octant (+6.4 sigma)
  constexpr int PPT = CAP/64 + 1;       // 20 regs/thread (wrap margin)
  constexpr int PP2 = PPT/2;            // 10
  __shared__ float4 SP[NW*CAP];         // staging, then re-indexed by orig idx
  __shared__ unsigned short WX[M];      // winner orig-idx per iteration
  __shared__ u64 part[2][NW];
  __shared__ u32 cnt[NW];
  __shared__ u32 blo[NW][3], bhi[NW][3];
  const int b = blockIdx.x;
  const float* P = pts + (size_t)b * N * 3;
  float* O = npts + (size_t)b * M * 3;
  const int tid = threadIdx.x, lane = tid & 63, wv = tid >> 6;

  if (tid < NW) cnt[tid] = 0;
  if (tid < NW*3){ ((u32*)blo)[tid] = 0xFFFFFFFFu; ((u32*)bhi)[tid] = 0u; }
  __syncthreads();

  // octant compaction + bbox (slot order is irrelevant to the output:
  // selection uses (value, min-orig-idx); per-point math is order-free)
  for (int i = tid; i < N; i += NT){
    const float x = P[3*i+0], y = P[3*i+1], z = P[3*i+2];
    const int oc = (x < 0.f ? 1 : 0) | (y < 0.f ? 2 : 0) | (z < 0.f ? 4 : 0);
    const u32 s = atomicAdd(&cnt[oc], 1u);
    if (s < CAP) SP[oc*CAP+s] = make_float4(x, y, z, __uint_as_float((u32)i));
    atomicMin(&blo[oc][0], fkey(x)); atomicMax(&bhi[oc][0], fkey(x));
    atomicMin(&blo[oc][1], fkey(y)); atomicMax(&bhi[oc][1], fkey(y));
    atomicMin(&blo[oc][2], fkey(z)); atomicMax(&bhi[oc][2], fkey(z));
  }
  __syncthreads();

  // register load (fillers = duplicates of real slots, keep real orig idx)
  const u32 cw = cnt[wv];
  const int base = wv * CAP;
  f2 X[PP2], Y[PP2], Z[PP2], MD[PP2];
  u32 OI[PPT];
#pragma unroll
  for (int k = 0; k < PPT; ++k){
    u32 s = (u32)lane + 64u*(u32)k;
    s = (s < cw) ? s : (s - cw);
    const float4 v = SP[base + s];
    OI[k] = __float_as_uint(v.w);
    if (k & 1){ X[k>>1].y = v.x; Y[k>>1].y = v.y; Z[k>>1].y = v.z; }
    else      { X[k>>1].x = v.x; Y[k>>1].x = v.y; Z[k>>1].x = v.z; }
  }
  const float lox = unfkey(blo[wv][0]), loy = unfkey(blo[wv][1]), loz = unfkey(blo[wv][2]);
  const float hix = unfkey(bhi[wv][0]), hiy = unfkey(bhi[wv][1]), hiz = unfkey(bhi[wv][2]);
  __syncthreads();

  // rewrite table indexed by ORIGINAL index (duplicate writes carry same data)
#pragma unroll
  for (int k = 0; k < PPT; ++k){
    const float xx = (k&1) ? X[k>>1].y : X[k>>1].x;
    const float yy = (k&1) ? Y[k>>1].y : Y[k>>1].x;
    const float zz = (k&1) ? Z[k>>1].y : Z[k>>1].x;
    SP[OI[k]] = make_float4(xx, yy, zz, 0.0f);
  }
  if (tid == 0) WX[0] = 0;
  __syncthreads();

// candidate = ~min(origidx among own minds == wave max); 0 if not at max
#define MAKECAND(dst, wkbits)                                                 \
  {                                                                           \
    u32 mo = 0xFFFFFFFFu;                                                     \
    if (__float_as_uint(bm) == (wkbits)){                                     \
      _Pragma("unroll")                                                       \
      for (int k = 0; k < PPT; ++k){                                          \
        const float mk = (k&1) ? MD[k>>1].y : MD[k>>1].x;                     \
        if (__float_as_uint(mk) == (wkbits)) mo = mo < OI[k] ? mo : OI[k];    \
      }                                                                       \
    }                                                                         \
    (dst) = ~mo;                                                              \
  }

#define TREEBM(tarr)                                                          \
  _Pragma("unroll")                                                           \
  for (int i = 0; i < 5; ++i) tarr[i] = f2max(tarr[i], tarr[i+5]);            \
  _Pragma("unroll")                                                           \
  for (int i = 0; i < 2; ++i) tarr[i] = f2max(tarr[i], tarr[i+3]);            \
  tarr[0] = f2max(tarr[0], tarr[2]);                                          \
  tarr[0] = f2max(tarr[0], tarr[1]);                                          \
  bm = fmaxf(tarr[0].x, tarr[0].y);

  // initial minds vs original point 0
  const float c0x = P[0], c0y = P[1], c0z = P[2];
  float bm;
  {
    const f2 cx2 = {c0x,c0x}, cy2 = {c0y,c0y}, cz2 = {c0z,c0z};
    f2 t[PP2];
#pragma unroll
    for (int j = 0; j < PP2; ++j){
      const f2 dx = X[j]-cx2, dy = Y[j]-cy2, dz = Z[j]-cz2;
      MD[j] = ((dx*dx) + (dy*dy)) + (dz*dz);
      t[j] = MD[j];
    }
    TREEBM(t)
  }
  u64 mypk;
  {
    const u32 wk = wave64_maxu(__float_as_uint(bm));
    u32 wc; MAKECAND(wc, wk);
    wc = wave64_maxu(wc);
    mypk = ((u64)wk << 32) | wc;
  }

  for (int it = 1; it < M; ++it){
    if (lane == 63) part[it & 1][wv] = mypk;
    __syncthreads();                    // LDS-only loop: no vmcnt drain
    const u64 best = red8_max64(part[it & 1][lane & (NW-1)]);
    const u32 widx = ~(u32)best;
    if (tid == 0) WX[it] = (unsigned short)widx;
    const float4 c = SP[widx];          // single b128 broadcast read
    // exact skip: LB(c, octant bbox)^2 * 0.98 >= max(own mind) ?
    const float tdx = fmaxf(0.0f, fmaxf(lox - c.x, c.x - hix));
    const float tdy = fmaxf(0.0f, fmaxf(loy - c.y, c.y - hiy));
    const float tdz = fmaxf(0.0f, fmaxf(loz - c.z, c.z - hiz));
    const float lb2 = ((tdx*tdx + tdy*tdy) + tdz*tdz) * 0.98f;
    const float wkf = __uint_as_float((u32)(mypk >> 32));
    const int doup = __builtin_amdgcn_readfirstlane(lb2 < wkf ? 1 : 0);
    if (doup){
      const f2 cx2 = {c.x,c.x}, cy2 = {c.y,c.y}, cz2 = {c.z,c.z};
      f2 t[PP2];
#pragma unroll
      for (int j = 0; j < PP2; ++j){
        const f2 dx = X[j]-cx2, dy = Y[j]-cy2, dz = Z[j]-cz2;
        const f2 d = ((dx*dx) + (dy*dy)) + (dz*dz);
        MD[j].x = fminf(MD[j].x, d.x);
        MD[j].y = fminf(MD[j].y, d.y);
        t[j] = MD[j];
      }
      TREEBM(t)
      const u32 wk = wave64_maxu(__float_as_uint(bm));
      u32 wc; MAKECAND(wc, wk);
      wc = wave64_maxu(wc);
      mypk = ((u64)wk << 32) | wc;
    }
  }
  __syncthreads();
  // epilogue: write all selected coords (global stores only here)
  for (int j = tid; j < M; j += NT){
    const float4 v = SP[WX[j]];
    O[3*j+0] = v.x; O[3*j+1] = v.y; O[3*j+2] = v.z;
  }
#undef MAKECAND
#undef TREEBM
}

// ---------------------------------------------------------------------------
// top-4 (ascending) insertion + cross-lane merge helpers
// ---------------------------------------------------------------------------
__device__ __forceinline__ void top4_insert(u64& a0,u64& a1,u64& a2,u64& a3, u64 p){
  if (p < a3){
    const bool c2 = p < a2, c1 = p < a1, c0 = p < a0;
    const u64 n3 = c2 ? a2 : p;
    const u64 n2 = c2 ? (c1 ? a1 : p) : a2;
    const u64 n1 = c1 ? (c0 ? a0 : p) : a1;
    const u64 n0 = c0 ? p : a0;
    a0=n0; a1=n1; a2=n2; a3=n3;
  }
}

__device__ __forceinline__ void merge4(u64& a0, u64& a1, u64& a2, u64& a3, int st)
{
  const u64 b0 = shfl_xor64(a0, st);
  const u64 b1 = shfl_xor64(a1, st);
  const u64 b2 = shfl_xor64(a2, st);
  const u64 b3 = shfl_xor64(a3, st);
  const u64 m0 = umin64(a0, b3);
  const u64 m1 = umin64(a1, b2);
  const u64 m2 = umin64(a2, b1);
  const u64 m3 = umin64(a3, b0);
  const u64 lo02 = umin64(m0,m2), hi02 = umax64(m0,m2);
  const u64 lo13 = umin64(m1,m3), hi13 = umax64(m1,m3);
  a0 = umin64(lo02, lo13); a1 = umax64(lo02, lo13);
  a2 = umin64(hi02, hi13); a3 = umax64(hi02, hi13);
}

// ---------------------------------------------------------------------------
// Level-1: kNN(k=4) + MLP(3->8->16->16) + max over k -> f1
// ---------------------------------------------------------------------------
template<int N, int M, int CH>
__global__ __launch_bounds__(256)
void knn_mlp1_kernel(const float* __restrict__ q, const float* __restrict__ pts,
                     const float* __restrict__ w1, const float* __restrict__ b1,
                     const float* __restrict__ w2, const float* __restrict__ b2,
                     const float* __restrict__ w3, const float* __restrict__ b3,
                     float* __restrict__ f1)
{
  __shared__ float4 s4[CH];
  constexpr int QPB = 64;
  const int blk = blockIdx.x;
  const int b = blk / (M / QPB);
  const int chunk = blk % (M / QPB);
  const int tid = threadIdx.x;
  const int g = tid >> 2;
  const int r = tid & 3;
  const int qi = chunk * QPB + g;
  const float* qp = q + ((size_t)b * M + qi) * 3;
  const float qx = qp[0], qy = qp[1], qz = qp[2];
  const float sumq = rn_add(rn_add(rn_mul(qx,qx), rn_mul(qy,qy)), rn_mul(qz,qz));
  const float* P = pts + (size_t)b * N * 3;

  u64 a0=~0ull, a1=~0ull, a2=~0ull, a3=~0ull;
  for (int c0 = 0; c0 < N; c0 += CH){
    for (int i = tid; i < CH; i += 256){
      const float x = P[3*(c0+i)+0], y = P[3*(c0+i)+1], z = P[3*(c0+i)+2];
      s4[i] = make_float4(x, y, z,
          rn_add(rn_add(rn_mul(x,x), rn_mul(y,y)), rn_mul(z,z)));
    }
    __syncthreads();
#pragma unroll 4
    for (int jj = r; jj < CH; jj += 4){
      const float4 v = s4[jj];
      const float dot = rn_add(rn_add(rn_mul(qx,v.x), rn_mul(qy,v.y)),
                               rn_mul(qz,v.z));
      const float d = rn_add(rn_sub(sumq, rn_mul(2.0f, dot)), v.w);
      top4_insert(a0,a1,a2,a3, ((u64)fkey(d) << 32) | (u32)(c0+jj));
    }
    __syncthreads();
  }
  merge4(a0,a1,a2,a3,1);
  merge4(a0,a1,a2,a3,2);
  const u64 selp = (r==0) ? a0 : (r==1) ? a1 : (r==2) ? a2 : a3;
  const u32 nidx = (u32)selp;

  const float nx = P[3*nidx+0], ny = P[3*nidx+1], nz = P[3*nidx+2];
  float h1[8];
#pragma unroll
  for (int c = 0; c < 8; ++c){
    float acc = b1[c];
    acc = fmaf(nx, w1[0*8+c], acc);
    acc = fmaf(ny, w1[1*8+c], acc);
    acc = fmaf(nz, w1[2*8+c], acc);
    h1[c] = fmaxf(acc, 0.0f);
  }
  float h2[16];
#pragma unroll
  for (int c = 0; c < 16; ++c){
    float acc = b2[c];
#pragma unroll
    for (int k = 0; k < 8; ++k) acc = fmaf(h1[k], w2[k*16+c], acc);
    h2[c] = fmaxf(acc, 0.0f);
  }
  float* fo = f1 + ((size_t)b * M + qi) * 16;
#pragma unroll
  for (int c = 0; c < 16; ++c){
    float acc = b3[c];
#pragma unroll
    for (int k = 0; k < 16; ++k) acc = fmaf(h2[k], w3[k*16+c], acc);
    float v = fmaxf(acc, 0.0f);
    v = fmaxf(v, __shfl_xor(v, 1, 64));
    v = fmaxf(v, __shfl_xor(v, 2, 64));
    if (r == 0) fo[c] = v;
  }
}

// ---------------------------------------------------------------------------
// Level-2: kNN(k=4) over npts1 + gather f1 + MLP(16->32->64->64) + max -> f2
// Queries = first 512 rows of npts1 (FPS nesting property, exact).
// ---------------------------------------------------------------------------
__global__ __launch_bounds__(256)
void knn_mlp2_kernel(const float* __restrict__ q, const float* __restrict__ pts,
                     const float* __restrict__ f1,
                     const float* __restrict__ w1, const float* __restrict__ b1,
                     const float* __restrict__ w2, const float* __restrict__ b2,
                     const float* __restrict__ w3, const float* __restrict__ b3,
                     float* __restrict__ f2)
{
  constexpr int N = 2048, M = 512, QPB = 64, QSTR = 2048;
  __shared__ float4 s4[N];
  const int blk = blockIdx.x;
  const int b = blk / (M / QPB);
  const int chunk = blk % (M / QPB);
  const int tid = threadIdx.x;
  const int g = tid >> 2;
  const int r = tid & 3;
  const int qi = chunk * QPB + g;
  const float* qp = q + ((size_t)b * QSTR + qi) * 3;
  const float qx = qp[0], qy = qp[1], qz = qp[2];
  const float sumq = rn_add(rn_add(rn_mul(qx,qx), rn_mul(qy,qy)), rn_mul(qz,qz));
  const float* P = pts + (size_t)b * N * 3;

  for (int i = tid; i < N; i += 256){
    const float x = P[3*i+0], y = P[3*i+1], z = P[3*i+2];
    s4[i] = make_float4(x, y, z,
        rn_add(rn_add(rn_mul(x,x), rn_mul(y,y)), rn_mul(z,z)));
  }
  __syncthreads();

  u64 a0=~0ull, a1=~0ull, a2=~0ull, a3=~0ull;
#pragma unroll 4
  for (int j = r; j < N; j += 4){
    const float4 v = s4[j];
    const float dot = rn_add(rn_add(rn_mul(qx,v.x), rn_mul(qy,v.y)),
                             rn_mul(qz,v.z));
    const float d = rn_add(rn_sub(sumq, rn_mul(2.0f, dot)), v.w);
    top4_insert(a0,a1,a2,a3, ((u64)fkey(d) << 32) | (u32)j);
  }
  merge4(a0,a1,a2,a3,1);
  merge4(a0,a1,a2,a3,2);
  const u64 selp = (r==0) ? a0 : (r==1) ? a1 : (r==2) ? a2 : a3;
  const u32 nidx = (u32)selp;

  const float* fv = f1 + ((size_t)b * 2048 + nidx) * 16;
  float x[16];
#pragma unroll
  for (int i = 0; i < 4; ++i){
    const float4 v = ((const float4*)fv)[i];
    x[4*i+0]=v.x; x[4*i+1]=v.y; x[4*i+2]=v.z; x[4*i+3]=v.w;
  }
  float h1[32];
#pragma unroll
  for (int c = 0; c < 32; ++c){
    float acc = b1[c];
#pragma unroll
    for (int k = 0; k < 16; ++k) acc = fmaf(x[k], w1[k*32+c], acc);
    h1[c] = fmaxf(acc, 0.0f);
  }
  float h2[64];
#pragma unroll
  for (int c = 0; c < 64; ++c){
    float acc = b2[c];
#pragma unroll
    for (int k = 0; k < 32; ++k) acc = fmaf(h1[k], w2[k*64+c], acc);
    h2[c] = fmaxf(acc, 0.0f);
  }
  float* fo = f2 + ((size_t)b * M + qi) * 64;
#pragma unroll
  for (int c = 0; c < 64; ++c){
    float acc = b3[c];
#pragma unroll
    for (int k = 0; k < 64; ++k) acc = fmaf(h2[k], w3[k*64+c], acc);
    float v = fmaxf(acc, 0.0f);
    v = fmaxf(v, __shfl_xor(v, 1, 64));
    v = fmaxf(v, __shfl_xor(v, 2, 64));
    if (r == 0) fo[c] = v;
  }
}

// ---------------------------------------------------------------------------
// Level-3: MLP(64->128->256->256) on f2 + global max over 512 points/batch.
// ---------------------------------------------------------------------------
__global__ __launch_bounds__(256)
void mlp3_kernel(const float* __restrict__ f2,
                 const float* __restrict__ w1, const float* __restrict__ b1,
                 const float* __restrict__ w2, const float* __restrict__ b2,
                 const float* __restrict__ w3, const float* __restrict__ b3,
                 float* __restrict__ out)
{
  constexpr int P = 16;
  __shared__ float X [P][64];
  __shared__ float H1[P][128];
  __shared__ float H2[P][256];
  __shared__ float PM[4][256];
  const int blk = blockIdx.x;
  const int b  = blk >> 5;
  const int pc = blk & 31;
  const int tid = threadIdx.x;
  const float* F = f2 + ((size_t)b * 512 + (size_t)pc * P) * 64;
  { const float4 v = ((const float4*)F)[tid]; ((float4*)&X[0][0])[tid] = v; }
  __syncthreads();
  {
    const int p = tid >> 4, c0 = (tid & 15) * 8;
    float acc[8];
#pragma unroll
    for (int i = 0; i < 8; ++i) acc[i] = b1[c0+i];
    for (int k = 0; k < 64; ++k){
      const float xv = X[p][k];
      const float4 wa = *(const float4*)&w1[k*128 + c0];
      const float4 wb = *(const float4*)&w1[k*128 + c0 + 4];
      acc[0]=fmaf(xv,wa.x,acc[0]); acc[1]=fmaf(xv,wa.y,acc[1]);
      acc[2]=fmaf(xv,wa.z,acc[2]); acc[3]=fmaf(xv,wa.w,acc[3]);
      acc[4]=fmaf(xv,wb.x,acc[4]); acc[5]=fmaf(xv,wb.y,acc[5]);
      acc[6]=fmaf(xv,wb.z,acc[6]); acc[7]=fmaf(xv,wb.w,acc[7]);
    }
#pragma unroll
    for (int i = 0; i < 8; ++i) H1[p][c0+i] = fmaxf(acc[i], 0.0f);
  }
  __syncthreads();
  {
    const int p = tid >> 4, c0 = (tid & 15) * 16;
    float acc[16];
#pragma unroll
    for (int i = 0; i < 16; ++i) acc[i] = b2[c0+i];
    for (int k = 0; k < 128; ++k){
      const float xv = H1[p][k];
#pragma unroll
      for (int i4 = 0; i4 < 4; ++i4){
        const float4 wv = *(const float4*)&w2[k*256 + c0 + 4*i4];
        acc[4*i4+0]=fmaf(xv,wv.x,acc[4*i4+0]);
        acc[4*i4+1]=fmaf(xv,wv.y,acc[4*i4+1]);
        acc[4*i4+2]=fmaf(xv,wv.z,acc[4*i4+2]);
        acc[4*i4+3]=fmaf(xv,wv.w,acc[4*i4+3]);
      }
    }
#pragma unroll
    for (int i = 0; i < 16; ++i) H2[p][c0+i] = fmaxf(acc[i], 0.0f);
  }
  __syncthreads();
  {
    const int pg = tid >> 6, c0 = (tid & 63) * 4;
    float acc[4][4];
#pragma unroll
    for (int p4 = 0; p4 < 4; ++p4)
#pragma unroll
      for (int i = 0; i < 4; ++i) acc[p4][i] = b3[c0+i];
    for (int k = 0; k < 256; ++k){
      const float4 wv = *(const float4*)&w3[k*256 + c0];
#pragma unroll
      for (int p4 = 0; p4 < 4; ++p4){
        const float xv = H2[pg*4+p4][k];
        acc[p4][0]=fmaf(xv,wv.x,acc[p4][0]);
        acc[p4][1]=fmaf(xv,wv.y,acc[p4][1]);
        acc[p4][2]=fmaf(xv,wv.z,acc[p4][2]);
        acc[p4][3]=fmaf(xv,wv.w,acc[p4][3]);
      }
    }
    float4 mx;
    mx.x = fmaxf(fmaxf(fmaxf(acc[0][0],0.f),fmaxf(acc[1][0],0.f)),
                 fmaxf(fmaxf(acc[2][0],0.f),fmaxf(acc[3][0],0.f)));
    mx.y = fmaxf(fmaxf(fmaxf(acc[0][1],0.f),fmaxf(acc[1][1],0.f)),
                 fmaxf(fmaxf(acc[2][1],0.f),fmaxf(acc[3][1],0.f)));
    mx.z = fmaxf(fmaxf(fmaxf(acc[0][2],0.f),fmaxf(acc[1][2],0.f)),
                 fmaxf(fmaxf(acc[2][2],0.f),fmaxf(acc[3][2],0.f)));
    mx.w = fmaxf(fmaxf(fmaxf(acc[0][3],0.f),fmaxf(acc[1][3],0.f)),
                 fmaxf(fmaxf(acc[2][3],0.f),fmaxf(acc[3][3],0.f)));
    *(float4*)&PM[pg][c0] = mx;
  }
  __syncthreads();
  {
    const float m = fmaxf(fmaxf(PM[0][tid], PM[1][tid]),
                          fmaxf(PM[2][tid], PM[3][tid]));
    atomicMax((int*)(out + b*256 + tid), __float_as_int(m));
  }
}

// ---------------------------------------------------------------------------
extern "C" void kernel_launch(void* const* d_in, const int* in_sizes, int n_in,
                              void* d_out, int out_size, void* d_ws, size_t ws_size,
                              hipStream_t stream)
{
  const float* pts  = (const float*)d_in[0];
  // d_in[1] = batch (int64) -- implied by uniform layout, unused
  const float* p1w1 = (const float*)d_in[2];
  const float* p1b1 = (const float*)d_in[3];
  const float* p1w2 = (const float*)d_in[4];
  const float* p1b2 = (const float*)d_in[5];
  const float* p1w3 = (const float*)d_in[6];
  const float* p1b3 = (const float*)d_in[7];
  const float* p2w1 = (const float*)d_in[8];
  const float* p2b1 = (const float*)d_in[9];
  const float* p2w2 = (const float*)d_in[10];
  const float* p2b2 = (const float*)d_in[11];
  const float* p2w3 = (const float*)d_in[12];
  const float* p2b3 = (const float*)d_in[13];
  const float* p3w1 = (const float*)d_in[14];
  const float* p3b1 = (const float*)d_in[15];
  const float* p3w2 = (const float*)d_in[16];
  const float* p3b2 = (const float*)d_in[17];
  const float* p3w3 = (const float*)d_in[18];
  const float* p3b3 = (const float*)d_in[19];

  float* ws = (float*)d_ws;
  size_t o = 0;
  float* npts1 = ws + o; o += (size_t)8*2048*3;
  float* f1    = ws + o; o += (size_t)8*2048*16;
  float* f2    = ws + o; o += (size_t)8*512*64;

  fps_kernel<8192,512,2048><<<8, 512, 0, stream>>>(pts, npts1);
  knn_mlp1_kernel<8192,2048,2048><<<8*32, 256, 0, stream>>>(npts1, pts,
      p1w1, p1b1, p1w2, p1b2, p1w3, p1b3, f1);
  // fps level-2 eliminated: fps(npts1,512) == npts1[:512] (nesting property)
  knn_mlp2_kernel<<<8*8, 256, 0, stream>>>(npts1, npts1, f1,
      p2w1, p2b1, p2w2, p2b2, p2w3, p2b3, f2);
  hipMemsetAsync(d_out, 0, (size_t)out_size * sizeof(float), stream);
  mlp3_kernel<<<8*32, 256, 0, stream>>>(f2,
      p3w1, p3b1, p3w2, p3b2, p3w3, p3b3, (float*)d_out);
}

// Round 6
// 2251.402 us; speedup vs baseline: 1.0998x; 1.0998x over previous
//
#include <hip/hip_runtime.h>
#include <stdint.h>

typedef unsigned long long u64;
typedef unsigned int u32;
typedef float f2 __attribute__((ext_vector_type(2)));

__device__ __forceinline__ float rn_mul(float a, float b){ return __fmul_rn(a,b); }
__device__ __forceinline__ float rn_add(float a, float b){ return __fadd_rn(a,b); }
__device__ __forceinline__ float rn_sub(float a, float b){ return __fsub_rn(a,b); }

// monotone float->uint key (for knn; handles tiny negative cancellation)
__device__ __forceinline__ u32 fkey(float d){
  u32 b = __float_as_uint(d);
  return b ^ ((u32)((int)b >> 31) | 0x80000000u);
}

__device__ __forceinline__ u64 shfl_xor64(u64 v, int mask){
  int lo = __shfl_xor((int)(u32)v, mask, 64);
  int hi = __shfl_xor((int)(u32)(v >> 32), mask, 64);
  return ((u64)(u32)hi << 32) | (u32)lo;
}
__device__ __forceinline__ u64 umin64(u64 a, u64 b){ return a < b ? a : b; }
__device__ __forceinline__ u64 umax64(u64 a, u64 b){ return a > b ? a : b; }

// ---- 64-bit DPP max (old=src: invalid/shifted-in lanes harmless) ----------
template<int C>
__device__ __forceinline__ u64 dstep64(u64 v){
  const u32 l = (u32)__builtin_amdgcn_update_dpp((int)(u32)v, (int)(u32)v, C, 0xF, 0xF, false);
  const u32 h = (u32)__builtin_amdgcn_update_dpp((int)(u32)(v>>32), (int)(u32)(v>>32), C, 0xF, 0xF, false);
  const u64 o = ((u64)h << 32) | l;
  return o > v ? o : v;
}
// full-wave max: valid result in lane 63
__device__ __forceinline__ u64 wave64_max64(u64 v){
  v = dstep64<0x111>(v);  // row_shr:1
  v = dstep64<0x112>(v);  // row_shr:2
  v = dstep64<0x114>(v);  // row_shr:4
  v = dstep64<0x118>(v);  // row_shr:8
  v = dstep64<0x142>(v);  // row_bcast:15
  v = dstep64<0x143>(v);  // row_bcast:31
  return v;
}
// max over lanes 0..7 -> uniform value (via readlane broadcast)
__device__ __forceinline__ u64 red8_max64(u64 v){
  v = dstep64<0x111>(v);
  v = dstep64<0x112>(v);
  v = dstep64<0x114>(v);
  const u32 l = (u32)__builtin_amdgcn_readlane((int)(u32)v, 7);
  const u32 h = (u32)__builtin_amdgcn_readlane((int)(u32)(v>>32), 7);
  return ((u64)h << 32) | l;
}

__device__ __forceinline__ f2 f2max(f2 a, f2 b){
  f2 r; r.x = fmaxf(a.x,b.x); r.y = fmaxf(a.y,b.y); return r;
}

// ---------------------------------------------------------------------------
// FPS: one block per batch, full cloud, 16 pts/thread f2-packed in registers.
// Per iter: fused update+max -> local first-idx rescan -> ONE combined 64-bit
// DPP wave reduce ((valbits<<32)|~gidx) -> lane63 publishes u64 -> barrier ->
// b64 read + 3-step u64 DPP red8 -> coords via one b128 LDS broadcast.
// No global ops in the loop; winners to LDS u16 list, stored in epilogue.
// Tie semantics = jnp.argmax (max value, smallest index) exactly.
// ---------------------------------------------------------------------------
template<int N, int NT, int M>
__global__ __launch_bounds__(NT)
void fps_kernel(const float* __restrict__ pts, float* __restrict__ npts)
{
#pragma clang fp contract(off)
  constexpr int PPT = N / NT;          // 16
  constexpr int PP2 = PPT / 2;         // 8
  constexpr int NW  = NT / 64;         // 8
  __shared__ float4 sp[N];             // 128 KB coord table
  __shared__ unsigned short WX[M];     // winner idx per iteration
  __shared__ u64 part[2][NW];
  const int b = blockIdx.x;
  const float* P = pts + (size_t)b * N * 3;
  float* O = npts + (size_t)b * M * 3;
  const int tid = threadIdx.x, lane = tid & 63, wv = tid >> 6;

  for (int i = tid; i < N; i += NT)
    sp[i] = make_float4(P[3*i+0], P[3*i+1], P[3*i+2], 0.0f);
  if (tid == 0) WX[0] = 0;
  __syncthreads();

  f2 rx[PP2], ry[PP2], rz[PP2], mind[PP2];
  const float4 c0 = sp[0];
  float bm;
  {
    const f2 cx2 = {c0.x,c0.x}, cy2 = {c0.y,c0.y}, cz2 = {c0.z,c0.z};
    f2 t[PP2];
#pragma unroll
    for (int j = 0; j < PP2; ++j){
      const float4 va = sp[tid + (2*j+0)*NT];
      const float4 vb = sp[tid + (2*j+1)*NT];
      rx[j] = f2{va.x, vb.x}; ry[j] = f2{va.y, vb.y}; rz[j] = f2{va.z, vb.z};
      const f2 dx = rx[j]-cx2, dy = ry[j]-cy2, dz = rz[j]-cz2;
      mind[j] = ((dx*dx) + (dy*dy)) + (dz*dz);   // v_pk_*, IEEE rn
      t[j] = mind[j];
    }
#pragma unroll
    for (int s = PP2/2; s > 0; s >>= 1)
#pragma unroll
      for (int i = 0; i < s; ++i) t[i] = f2max(t[i], t[i+s]);
    bm = fmaxf(t[0].x, t[0].y);
  }

  // lane candidate: (value bits << 32) | ~min matching global idx
#define LANECAND(dst)                                                         \
  {                                                                           \
    u32 mo = 0xFFFFFFFFu;                                                     \
    _Pragma("unroll")                                                         \
    for (int j = PP2-1; j >= 0; --j){                                         \
      const u32 gb = (u32)(tid + (2*j+1)*NT);                                 \
      const u32 ga = (u32)(tid + (2*j+0)*NT);                                 \
      if (mind[j].y == bm) mo = gb;                                           \
      if (mind[j].x == bm) mo = ga;                                           \
    }                                                                         \
    (dst) = ((u64)__float_as_uint(bm) << 32) | (u64)(u32)~mo;                 \
  }

  u64 mypk;
  { u64 c; LANECAND(c); mypk = wave64_max64(c); }

  for (int it = 1; it < M; ++it){
    if (lane == 63) part[it & 1][wv] = mypk;
    __syncthreads();                   // LDS-only loop
    const u64 best = red8_max64(part[it & 1][lane & (NW-1)]);
    const u32 widx = ~(u32)best;
    if (tid == 0) WX[it] = (unsigned short)widx;
    const float4 c = sp[widx];         // single b128 broadcast read
    const f2 cx2 = {c.x,c.x}, cy2 = {c.y,c.y}, cz2 = {c.z,c.z};
    f2 t[PP2];
#pragma unroll
    for (int j = 0; j < PP2; ++j){
      const f2 dx = rx[j]-cx2, dy = ry[j]-cy2, dz = rz[j]-cz2;
      const f2 d = ((dx*dx) + (dy*dy)) + (dz*dz);
      mind[j].x = fminf(mind[j].x, d.x);
      mind[j].y = fminf(mind[j].y, d.y);
      t[j] = mind[j];
    }
#pragma unroll
    for (int s = PP2/2; s > 0; s >>= 1)
#pragma unroll
      for (int i = 0; i < s; ++i) t[i] = f2max(t[i], t[i+s]);
    bm = fmaxf(t[0].x, t[0].y);
    u64 cand; LANECAND(cand);
    mypk = wave64_max64(cand);
  }
  __syncthreads();
  // epilogue: the only global stores
  for (int j = tid; j < M; j += NT){
    const float4 v = sp[WX[j]];
    O[3*j+0] = v.x; O[3*j+1] = v.y; O[3*j+2] = v.z;
  }
#undef LANECAND
}

// ---------------------------------------------------------------------------
// top-4 (ascending) insertion + cross-lane merge helpers
// ---------------------------------------------------------------------------
__device__ __forceinline__ void top4_insert(u64& a0,u64& a1,u64& a2,u64& a3, u64 p){
  if (p < a3){
    const bool c2 = p < a2, c1 = p < a1, c0 = p < a0;
    const u64 n3 = c2 ? a2 : p;
    const u64 n2 = c2 ? (c1 ? a1 : p) : a2;
    const u64 n1 = c1 ? (c0 ? a0 : p) : a1;
    const u64 n0 = c0 ? p : a0;
    a0=n0; a1=n1; a2=n2; a3=n3;
  }
}

__device__ __forceinline__ void merge4(u64& a0, u64& a1, u64& a2, u64& a3, int st)
{
  const u64 b0 = shfl_xor64(a0, st);
  const u64 b1 = shfl_xor64(a1, st);
  const u64 b2 = shfl_xor64(a2, st);
  const u64 b3 = shfl_xor64(a3, st);
  const u64 m0 = umin64(a0, b3);
  const u64 m1 = umin64(a1, b2);
  const u64 m2 = umin64(a2, b1);
  const u64 m3 = umin64(a3, b0);
  const u64 lo02 = umin64(m0,m2), hi02 = umax64(m0,m2);
  const u64 lo13 = umin64(m1,m3), hi13 = umax64(m1,m3);
  a0 = umin64(lo02, lo13); a1 = umax64(lo02, lo13);
  a2 = umin64(hi02, hi13); a3 = umax64(hi02, hi13);
}

// ---------------------------------------------------------------------------
// Level-1: kNN(k=4) + MLP(3->8->16->16) + max over k -> f1
// ---------------------------------------------------------------------------
template<int N, int M, int CH>
__global__ __launch_bounds__(256)
void knn_mlp1_kernel(const float* __restrict__ q, const float* __restrict__ pts,
                     const float* __restrict__ w1, const float* __restrict__ b1,
                     const float* __restrict__ w2, const float* __restrict__ b2,
                     const float* __restrict__ w3, const float* __restrict__ b3,
                     float* __restrict__ f1)
{
  __shared__ float4 s4[CH];
  constexpr int QPB = 64;
  const int blk = blockIdx.x;
  const int b = blk / (M / QPB);
  const int chunk = blk % (M / QPB);
  const int tid = threadIdx.x;
  const int g = tid >> 2;
  const int r = tid & 3;
  const int qi = chunk * QPB + g;
  const float* qp = q + ((size_t)b * M + qi) * 3;
  const float qx = qp[0], qy = qp[1], qz = qp[2];
  const float sumq = rn_add(rn_add(rn_mul(qx,qx), rn_mul(qy,qy)), rn_mul(qz,qz));
  const float* P = pts + (size_t)b * N * 3;

  u64 a0=~0ull, a1=~0ull, a2=~0ull, a3=~0ull;
  for (int c0 = 0; c0 < N; c0 += CH){
    for (int i = tid; i < CH; i += 256){
      const float x = P[3*(c0+i)+0], y = P[3*(c0+i)+1], z = P[3*(c0+i)+2];
      s4[i] = make_float4(x, y, z,
          rn_add(rn_add(rn_mul(x,x), rn_mul(y,y)), rn_mul(z,z)));
    }
    __syncthreads();
#pragma unroll 4
    for (int jj = r; jj < CH; jj += 4){
      const float4 v = s4[jj];
      const float dot = rn_add(rn_add(rn_mul(qx,v.x), rn_mul(qy,v.y)),
                               rn_mul(qz,v.z));
      const float d = rn_add(rn_sub(sumq, rn_mul(2.0f, dot)), v.w);
      top4_insert(a0,a1,a2,a3, ((u64)fkey(d) << 32) | (u32)(c0+jj));
    }
    __syncthreads();
  }
  merge4(a0,a1,a2,a3,1);
  merge4(a0,a1,a2,a3,2);
  const u64 selp = (r==0) ? a0 : (r==1) ? a1 : (r==2) ? a2 : a3;
  const u32 nidx = (u32)selp;

  const float nx = P[3*nidx+0], ny = P[3*nidx+1], nz = P[3*nidx+2];
  float h1[8];
#pragma unroll
  for (int c = 0; c < 8; ++c){
    float acc = b1[c];
    acc = fmaf(nx, w1[0*8+c], acc);
    acc = fmaf(ny, w1[1*8+c], acc);
    acc = fmaf(nz, w1[2*8+c], acc);
    h1[c] = fmaxf(acc, 0.0f);
  }
  float h2[16];
#pragma unroll
  for (int c = 0; c < 16; ++c){
    float acc = b2[c];
#pragma unroll
    for (int k = 0; k < 8; ++k) acc = fmaf(h1[k], w2[k*16+c], acc);
    h2[c] = fmaxf(acc, 0.0f);
  }
  float* fo = f1 + ((size_t)b * M + qi) * 16;
#pragma unroll
  for (int c = 0; c < 16; ++c){
    float acc = b3[c];
#pragma unroll
    for (int k = 0; k < 16; ++k) acc = fmaf(h2[k], w3[k*16+c], acc);
    float v = fmaxf(acc, 0.0f);
    v = fmaxf(v, __shfl_xor(v, 1, 64));
    v = fmaxf(v, __shfl_xor(v, 2, 64));
    if (r == 0) fo[c] = v;
  }
}

// ---------------------------------------------------------------------------
// Level-2: kNN(k=4) over npts1 + gather f1 + MLP(16->32->64->64) + max -> f2
// Queries = first 512 rows of npts1 (FPS nesting property, exact).
// ---------------------------------------------------------------------------
__global__ __launch_bounds__(256)
void knn_mlp2_kernel(const float* __restrict__ q, const float* __restrict__ pts,
                     const float* __restrict__ f1,
                     const float* __restrict__ w1, const float* __restrict__ b1,
                     const float* __restrict__ w2, const float* __restrict__ b2,
                     const float* __restrict__ w3, const float* __restrict__ b3,
                     float* __restrict__ f2)
{
  constexpr int N = 2048, M = 512, QPB = 64, QSTR = 2048;
  __shared__ float4 s4[N];
  const int blk = blockIdx.x;
  const int b = blk / (M / QPB);
  const int chunk = blk % (M / QPB);
  const int tid = threadIdx.x;
  const int g = tid >> 2;
  const int r = tid & 3;
  const int qi = chunk * QPB + g;
  const float* qp = q + ((size_t)b * QSTR + qi) * 3;
  const float qx = qp[0], qy = qp[1], qz = qp[2];
  const float sumq = rn_add(rn_add(rn_mul(qx,qx), rn_mul(qy,qy)), rn_mul(qz,qz));
  const float* P = pts + (size_t)b * N * 3;

  for (int i = tid; i < N; i += 256){
    const float x = P[3*i+0], y = P[3*i+1], z = P[3*i+2];
    s4[i] = make_float4(x, y, z,
        rn_add(rn_add(rn_mul(x,x), rn_mul(y,y)), rn_mul(z,z)));
  }
  __syncthreads();

  u64 a0=~0ull, a1=~0ull, a2=~0ull, a3=~0ull;
#pragma unroll 4
  for (int j = r; j < N; j += 4){
    const float4 v = s4[j];
    const float dot = rn_add(rn_add(rn_mul(qx,v.x), rn_mul(qy,v.y)),
                             rn_mul(qz,v.z));
    const float d = rn_add(rn_sub(sumq, rn_mul(2.0f, dot)), v.w);
    top4_insert(a0,a1,a2,a3, ((u64)fkey(d) << 32) | (u32)j);
  }
  merge4(a0,a1,a2,a3,1);
  merge4(a0,a1,a2,a3,2);
  const u64 selp = (r==0) ? a0 : (r==1) ? a1 : (r==2) ? a2 : a3;
  const u32 nidx = (u32)selp;

  const float* fv = f1 + ((size_t)b * 2048 + nidx) * 16;
  float x[16];
#pragma unroll
  for (int i = 0; i < 4; ++i){
    const float4 v = ((const float4*)fv)[i];
    x[4*i+0]=v.x; x[4*i+1]=v.y; x[4*i+2]=v.z; x[4*i+3]=v.w;
  }
  float h1[32];
#pragma unroll
  for (int c = 0; c < 32; ++c){
    float acc = b1[c];
#pragma unroll
    for (int k = 0; k < 16; ++k) acc = fmaf(x[k], w1[k*32+c], acc);
    h1[c] = fmaxf(acc, 0.0f);
  }
  float h2[64];
#pragma unroll
  for (int c = 0; c < 64; ++c){
    float acc = b2[c];
#pragma unroll
    for (int k = 0; k < 32; ++k) acc = fmaf(h1[k], w2[k*64+c], acc);
    h2[c] = fmaxf(acc, 0.0f);
  }
  float* fo = f2 + ((size_t)b * M + qi) * 64;
#pragma unroll
  for (int c = 0; c < 64; ++c){
    float acc = b3[c];
#pragma unroll
    for (int k = 0; k < 64; ++k) acc = fmaf(h2[k], w3[k*64+c], acc);
    float v = fmaxf(acc, 0.0f);
    v = fmaxf(v, __shfl_xor(v, 1, 64));
    v = fmaxf(v, __shfl_xor(v, 2, 64));
    if (r == 0) fo[c] = v;
  }
}

// ---------------------------------------------------------------------------
// Level-3: MLP(64->128->256->256) on f2 + global max over 512 points/batch.
// ---------------------------------------------------------------------------
__global__ __launch_bounds__(256)
void mlp3_kernel(const float* __restrict__ f2,
                 const float* __restrict__ w1, const float* __restrict__ b1,
                 const float* __restrict__ w2, const float* __restrict__ b2,
                 const float* __restrict__ w3, const float* __restrict__ b3,
                 float* __restrict__ out)
{
  constexpr int P = 16;
  __shared__ float X [P][64];
  __shared__ float H1[P][128];
  __shared__ float H2[P][256];
  __shared__ float PM[4][256];
  const int blk = blockIdx.x;
  const int b  = blk >> 5;
  const int pc = blk & 31;
  const int tid = threadIdx.x;
  const float* F = f2 + ((size_t)b * 512 + (size_t)pc * P) * 64;
  { const float4 v = ((const float4*)F)[tid]; ((float4*)&X[0][0])[tid] = v; }
  __syncthreads();
  {
    const int p = tid >> 4, c0 = (tid & 15) * 8;
    float acc[8];
#pragma unroll
    for (int i = 0; i < 8; ++i) acc[i] = b1[c0+i];
    for (int k = 0; k < 64; ++k){
      const float xv = X[p][k];
      const float4 wa = *(const float4*)&w1[k*128 + c0];
      const float4 wb = *(const float4*)&w1[k*128 + c0 + 4];
      acc[0]=fmaf(xv,wa.x,acc[0]); acc[1]=fmaf(xv,wa.y,acc[1]);
      acc[2]=fmaf(xv,wa.z,acc[2]); acc[3]=fmaf(xv,wa.w,acc[3]);
      acc[4]=fmaf(xv,wb.x,acc[4]); acc[5]=fmaf(xv,wb.y,acc[5]);
      acc[6]=fmaf(xv,wb.z,acc[6]); acc[7]=fmaf(xv,wb.w,acc[7]);
    }
#pragma unroll
    for (int i = 0; i < 8; ++i) H1[p][c0+i] = fmaxf(acc[i], 0.0f);
  }
  __syncthreads();
  {
    const int p = tid >> 4, c0 = (tid & 15) * 16;
    float acc[16];
#pragma unroll
    for (int i = 0; i < 16; ++i) acc[i] = b2[c0+i];
    for (int k = 0; k < 128; ++k){
      const float xv = H1[p][k];
#pragma unroll
      for (int i4 = 0; i4 < 4; ++i4){
        const float4 wv = *(const float4*)&w2[k*256 + c0 + 4*i4];
        acc[4*i4+0]=fmaf(xv,wv.x,acc[4*i4+0]);
        acc[4*i4+1]=fmaf(xv,wv.y,acc[4*i4+1]);
        acc[4*i4+2]=fmaf(xv,wv.z,acc[4*i4+2]);
        acc[4*i4+3]=fmaf(xv,wv.w,acc[4*i4+3]);
      }
    }
#pragma unroll
    for (int i = 0; i < 16; ++i) H2[p][c0+i] = fmaxf(acc[i], 0.0f);
  }
  __syncthreads();
  {
    const int pg = tid >> 6, c0 = (tid & 63) * 4;
    float acc[4][4];
#pragma unroll
    for (int p4 = 0; p4 < 4; ++p4)
#pragma unroll
      for (int i = 0; i < 4; ++i) acc[p4][i] = b3[c0+i];
    for (int k = 0; k < 256; ++k){
      const float4 wv = *(const float4*)&w3[k*256 + c0];
#pragma unroll
      for (int p4 = 0; p4 < 4; ++p4){
        const float xv = H2[pg*4+p4][k];
        acc[p4][0]=fmaf(xv,wv.x,acc[p4][0]);
        acc[p4][1]=fmaf(xv,wv.y,acc[p4][1]);
        acc[p4][2]=fmaf(xv,wv.z,acc[p4][2]);
        acc[p4][3]=fmaf(xv,wv.w,acc[p4][3]);
      }
    }
    float4 mx;
    mx.x = fmaxf(fmaxf(fmaxf(acc[0][0],0.f),fmaxf(acc[1][0],0.f)),
                 fmaxf(fmaxf(acc[2][0],0.f),fmaxf(acc[3][0],0.f)));
    mx.y = fmaxf(fmaxf(fmaxf(acc[0][1],0.f),fmaxf(acc[1][1],0.f)),
                 fmaxf(fmaxf(acc[2][1],0.f),fmaxf(acc[3][1],0.f)));
    mx.z = fmaxf(fmaxf(fmaxf(acc[0][2],0.f),fmaxf(acc[1][2],0.f)),
                 fmaxf(fmaxf(acc[2][2],0.f),fmaxf(acc[3][2],0.f)));
    mx.w = fmaxf(fmaxf(fmaxf(acc[0][3],0.f),fmaxf(acc[1][3],0.f)),
                 fmaxf(fmaxf(acc[2][3],0.f),fmaxf(acc[3][3],0.f)));
    *(float4*)&PM[pg][c0] = mx;
  }
  __syncthreads();
  {
    const float m = fmaxf(fmaxf(PM[0][tid], PM[1][tid]),
                          fmaxf(PM[2][tid], PM[3][tid]));
    atomicMax((int*)(out + b*256 + tid), __float_as_int(m));
  }
}

// ---------------------------------------------------------------------------
extern "C" void kernel_launch(void* const* d_in, const int* in_sizes, int n_in,
                              void* d_out, int out_size, void* d_ws, size_t ws_size,
                              hipStream_t stream)
{
  const float* pts  = (const float*)d_in[0];
  // d_in[1] = batch (int64) -- implied by uniform layout, unused
  const float* p1w1 = (const float*)d_in[2];
  const float* p1b1 = (const float*)d_in[3];
  const float* p1w2 = (const float*)d_in[4];
  const float* p1b2 = (const float*)d_in[5];
  const float* p1w3 = (const float*)d_in[6];
  const float* p1b3 = (const float*)d_in[7];
  const float* p2w1 = (const float*)d_in[8];
  const float* p2b1 = (const float*)d_in[9];
  const float* p2w2 = (const float*)d_in[10];
  const float* p2b2 = (const float*)d_in[11];
  const float* p2w3 = (const float*)d_in[12];
  const float* p2b3 = (const float*)d_in[13];
  const float* p3w1 = (const float*)d_in[14];
  const float* p3b1 = (const float*)d_in[15];
  const float* p3w2 = (const float*)d_in[16];
  const float* p3b2 = (const float*)d_in[17];
  const float* p3w3 = (const float*)d_in[18];
  const float* p3b3 = (const float*)d_in[19];

  float* ws = (float*)d_ws;
  size_t o = 0;
  float* npts1 = ws + o; o += (size_t)8*2048*3;
  float* f1    = ws + o; o += (size_t)8*2048*16;
  float* f2    = ws + o; o += (size_t)8*512*64;

  fps_kernel<8192,512,2048><<<8, 512, 0, stream>>>(pts, npts1);
  knn_mlp1_kernel<8192,2048,2048><<<8*32, 256, 0, stream>>>(npts1, pts,
      p1w1, p1b1, p1w2, p1b2, p1w3, p1b3, f1);
  // fps level-2 eliminated: fps(npts1,512) == npts1[:512] (nesting property)
  knn_mlp2_kernel<<<8*8, 256, 0, stream>>>(npts1, npts1, f1,
      p2w1, p2b1, p2w2, p2b2, p2w3, p2b3, f2);
  hipMemsetAsync(d_out, 0, (size_t)out_size * sizeof(float), stream);
  mlp3_kernel<<<8*32, 256, 0, stream>>>(f2,
      p3w1, p3b1, p3w2, p3b2, p3w3, p3b3, (float*)d_out);
}